// Round 1
// 123.994 us; speedup vs baseline: 1.4269x; 1.4269x over previous
//
#include <hip/hip_runtime.h>
#include <cstdint>
#include <cstddef>

#define BB 16
#define NN 4096
#define CC 80
#define MAXD 100
#define CONF_T 0.5f
#define RSTRIDE 81
#define PER_B (MAXD * 4 + MAXD * CC)   // 8400 output elems per batch
#define NWORDS 64                      // 4096/64 bitmap words (fallback)
#define BCAP 4096                      // B-group capacity (no truncation)
#define FBCAP 2048                     // fallback kernel's capacity
#define SEGSZ 2048
#define CH 1024                        // lazy-refill chunk (1 entry/thread)
#define CCAP 1088                      // clean-list cap: 63 leftover + 1024 chunk

// fl32(inter/uni) > 0.5  <=>  inter > uni*(0.5+2^-25), evaluated EXACTLY in
// fp64 (24-bit x 25-bit mantissa product = 49 bits < 53). Bit-identical to
// the reference's IEEE divide + compare. (verified passing rounds 9)
#define IOUC 0x1.000001p-1

// ---- workspace layout (fast path) ----
#define WS_KEYS   0x000000             // [B*N] u64
#define WS_NLIST  0x1C0000             // [B] int (unused by fused path; kept)
#define WS_KIDX   0x1C0100             // [B*100] int
#define WS_CNT    0x1C2000             // [B] int
#define WS_NEED   0x200000             // 2 MB

// ---------------------------------------------------------------------------
// K1: softmax of (10x)^2 per row, one THREAD per row, 128 rows/block.
// numpy pairwise-8 sum DAG for s (bitwise == np); score = IEEE fl(1/s).
// ---------------------------------------------------------------------------
__global__ __launch_bounds__(128) void k_softmax(const float* __restrict__ cls_in,
                                                 float* __restrict__ probs,
                                                 uint64_t* __restrict__ keys) {
#pragma clang fp contract(off)
    __shared__ float buf[128 * RSTRIDE];
    int t = threadIdx.x;
    size_t gbase = (size_t)blockIdx.x * 128 * CC;

    for (int i = t; i < 128 * CC; i += 128) {
        int r = i / CC, c = i - r * CC;
        buf[r * RSTRIDE + c] = cls_in[gbase + i];
    }
    __syncthreads();

    float* row = buf + t * RSTRIDE;

    float m = -3.402823466e+38f;
    for (int c = 0; c < CC; ++c) {
        float y = row[c] * 10.0f;
        float z = y * y;
        m = fmaxf(m, z);
    }
    for (int c = 0; c < CC; ++c) {
        float y = row[c] * 10.0f;
        float z = y * y;
        row[c] = expf(z - m);
    }
    float r8[8];
    #pragma unroll
    for (int j = 0; j < 8; ++j) r8[j] = row[j];
    for (int i = 8; i < CC; i += 8) {
        #pragma unroll
        for (int j = 0; j < 8; ++j) r8[j] += row[i + j];
    }
    float s = ((r8[0] + r8[1]) + (r8[2] + r8[3])) + ((r8[4] + r8[5]) + (r8[6] + r8[7]));

    float score = 1.0f / s;
    for (int c = 0; c < CC; ++c) row[c] = row[c] * score;

    int gw = blockIdx.x * 128 + t;
    unsigned n = (unsigned)(gw & (NN - 1));
    keys[gw] = ((uint64_t)__float_as_uint(score) << 32)
             | (uint64_t)(0xFFFFFFFFu - n);

    __syncthreads();
    for (int i = t; i < 128 * CC; i += 128) {
        int r = i / CC, c = i - r * CC;
        probs[gbase + i] = buf[r * RSTRIDE + c];
    }
}

// ---------------------------------------------------------------------------
// K2 (fused): partition + rank-sort + LDS corner build + LAZY-LIST NMS.
// One block (1024 thr = 16 waves) per batch.
//
// Replaces k_part + k_nms3. Key change vs the bitmap version: filtering cost
// scales with EXAMINED CANDIDATES x KEEPS, not 64-words x keeps x rounds.
// Clean list C holds, in ascending sorted order, all live candidates with
// position < cursor, each already checked vs every keep so far. Raw
// candidates are implicit: positions [cursor, nl). Per round:
//   refill: while |C|<64 and raw left, filter next 1024 raw vs ALL keeps,
//           stable-append survivors to C (first chunk: 0 keeps = free)
//   select: C[0..st) = st lowest live overall (raw entries are all >= cursor)
//   kill matrix + exact greedy replay: verbatim from the verified kernel
//   refilter: C[st..cc) vs only the NEW keeps, stable-compact to front
// done <=> kept>=100 or cc<64 (refill exhausted raw). Identical greedy order
// to the reference: keeps appended in ascending sorted position.
// ---------------------------------------------------------------------------
__global__ __launch_bounds__(1024) void k_pnms(const uint64_t* __restrict__ keys,
                                               const float* __restrict__ boxes,
                                               int* __restrict__ kidx_out,
                                               int* __restrict__ cnt_out) {
#pragma clang fp contract(off)
    __shared__ __align__(16) unsigned char sraw[6 * NN * 4];   // 96 KB
    float* hy1 = (float*)sraw;
    float* hx1 = (float*)(sraw + NN * 4);
    float* hy2 = (float*)(sraw + 2 * NN * 4);
    float* hx2 = (float*)(sraw + 3 * NN * 4);
    float* har = (float*)(sraw + 4 * NN * 4);
    int*   og  = (int*)(sraw + 5 * NN * 4);
    uint64_t* bbuf = (uint64_t*)sraw;          // overlays hy1+hx1 (32 KB); dead after sort
    __shared__ int clist[CCAP];
    __shared__ uint64_t kill[64];
    __shared__ int cand_s[64];
    __shared__ int kpos[MAXD];
    __shared__ int wsumA[16], wsumB[16], wsumC[16];
    __shared__ int kept_s, fk0_s, done_s, ccnt_s, cur_s;

    const int tid = threadIdx.x, lane = tid & 63, wv = tid >> 6;
    const int b = blockIdx.x;
    const uint64_t* kb = keys + (size_t)b * NN;
    const float* bxp = boxes + (size_t)b * NN * 4;

    // ---- partition (verbatim logic; og/bbuf now LDS, keys untouched) ----
    uint64_t myk[4]; bool fa[4], fb[4];
    int asum = 0, bsum = 0;
    for (int k = 0; k < 4; ++k) {
        uint64_t key = kb[4 * tid + k]; myk[k] = key;
        unsigned hi = (unsigned)(key >> 32);
        fa[k] = (hi == 0x3F800000u);
        fb[k] = (__uint_as_float(hi) > CONF_T) && !fa[k];
        asum += fa[k] ? 1 : 0; bsum += fb[k] ? 1 : 0;
    }
    int ia = asum, ib = bsum;                       // wave-inclusive scans
    for (int off = 1; off < 64; off <<= 1) {
        int va = __shfl_up(ia, off), vb = __shfl_up(ib, off);
        if (lane >= off) { ia += va; ib += vb; }
    }
    if (lane == 63) { wsumA[wv] = ia; wsumB[wv] = ib; }
    __syncthreads();
    int baseA = 0, baseB = 0, cntA = 0, cntB = 0;
    for (int w2 = 0; w2 < 16; ++w2) {
        if (w2 < wv) { baseA += wsumA[w2]; baseB += wsumB[w2]; }
        cntA += wsumA[w2]; cntB += wsumB[w2];
    }
    int pA = baseA + (ia - asum);
    int pB = baseB + (ib - bsum);
    for (int k = 0; k < 4; ++k) {
        if (fa[k]) og[pA++] = 4 * tid + k;          // stable: idx order
        if (fb[k]) bbuf[pB++] = myk[k];             // pB < cntB <= 4096 always
    }
    __syncthreads();

    // ---- rank sort of B (descending, keys unique): one barrier ----
    for (int i = tid; i < cntB; i += 1024) {
        uint64_t ki = bbuf[i];
        int rank = 0;
        for (int j = 0; j < cntB; ++j) rank += (bbuf[j] > ki) ? 1 : 0;
        og[cntA + rank] = (int)(0xFFFFFFFFu - (unsigned)(ki & 0xFFFFFFFFull));
    }
    int nl = cntA + cntB; if (nl > NN) nl = NN;
    __syncthreads();   // bbuf reads done; og complete

    // ---- sorted corner build into LDS (overwrites bbuf region) ----
    for (int i = tid; i < nl; i += 1024) {
        int o = og[i];
        float4 bv = ((const float4*)bxp)[o];
        float y1 = fminf(bv.x, bv.z), y2 = fmaxf(bv.x, bv.z);
        float x1 = fminf(bv.y, bv.w), x2 = fmaxf(bv.y, bv.w);
        hy1[i] = y1; hx1[i] = x1; hy2[i] = y2; hx2[i] = x2;
        har[i] = (y2 - y1) * (x2 - x1);
    }
    if (tid == 0) { kept_s = 0; fk0_s = 0; done_s = 0; ccnt_s = 0; cur_s = 0; }

    // ---- rounds ----
    for (;;) {
        __syncthreads();                               // B1
        // -- refill clean list from raw [cursor, nl) --
        for (;;) {
            int cc0 = ccnt_s, cur = cur_s;
            if (cc0 >= 64 || cur >= nl) break;         // uniform
            int i = cur + tid;
            bool v = i < nl;
            int ii = v ? i : 0;
            float y1 = hy1[ii], x1 = hx1[ii], y2 = hy2[ii], x2 = hx2[ii], ar = har[ii];
            bool sup = false;
            int f1 = kept_s;                           // < MAXD here (else done)
            for (int q0 = 0; q0 < f1; q0 += 64) {
                int qi = q0 + lane;
                int kp = (qi < f1) ? kpos[qi] : 0;
                float ky1 = hy1[kp], kx1 = hx1[kp], ky2 = hy2[kp], kx2 = hx2[kp], kar = har[kp];
                int qn = f1 - q0; if (qn > 64) qn = 64;
                bool deadall = false;
                for (int q = 0; q < qn; ++q) {
                    float qy1 = __shfl(ky1, q), qx1 = __shfl(kx1, q);
                    float qy2 = __shfl(ky2, q), qx2 = __shfl(kx2, q);
                    float qar = __shfl(kar, q);
                    float ih = fmaxf(0.f, fminf(y2, qy2) - fmaxf(y1, qy1));
                    float iw = fmaxf(0.f, fminf(x2, qx2) - fmaxf(x1, qx1));
                    float inter = ih * iw;
                    float uni = (ar + qar) - inter;
                    sup = sup || (inter > 0.f && (double)inter > (double)uni * IOUC);
                    if ((q & 7) == 7 && __ballot(v && !sup) == 0ull) { deadall = true; break; }
                }
                if (deadall) break;
            }
            bool srv = v && !sup;
            int sflag = srv ? 1 : 0;
            int inc = sflag;
            for (int off = 1; off < 64; off <<= 1) {
                int v2 = __shfl_up(inc, off);
                if (lane >= off) inc += v2;
            }
            if (lane == 63) wsumC[wv] = inc;
            __syncthreads();                           // BA: scan ready, reads done
            int base = 0, tot = 0;
            for (int w2 = 0; w2 < 16; ++w2) {
                int s2 = wsumC[w2];
                if (w2 < wv) base += s2;
                tot += s2;
            }
            if (srv) clist[cc0 + base + (inc - sflag)] = i;   // stable append
            if (tid == 0) { ccnt_s = cc0 + tot; cur_s = cur + CH; }
            __syncthreads();                           // BB: writes visible
        }
        int cc = ccnt_s;
        int st = cc < 64 ? cc : 64;
        if (tid < 64) cand_s[tid] = (tid < st) ? clist[tid] : -1;
        __syncthreads();                               // B2
        if (st <= 0) break;

        // -- 64x64 intra-batch kill matrix: wave w rows t = w+16r (verbatim) --
        {
            int cj = cand_s[lane];
            bool jv = cj >= 0;
            int cjx = jv ? cj : 0;
            float jy1 = hy1[cjx], jx1 = hx1[cjx], jy2 = hy2[cjx], jx2 = hx2[cjx], jar = har[cjx];
            #pragma unroll
            for (int r = 0; r < 4; ++r) {
                int t = wv + 16 * r;
                int ct = cand_s[t];
                bool tv = ct >= 0;
                int ctx = tv ? ct : 0;
                float ty1 = hy1[ctx], tx1 = hx1[ctx], ty2 = hy2[ctx], tx2 = hx2[ctx], tar = har[ctx];
                float ih = fmaxf(0.f, fminf(ty2, jy2) - fmaxf(ty1, jy1));
                float iw = fmaxf(0.f, fminf(tx2, jx2) - fmaxf(tx1, jx1));
                float inter = ih * iw;
                float uni = (tar + jar) - inter;
                bool s = tv && jv && (inter > 0.f) && ((double)inter > (double)uni * IOUC);
                uint64_t w = __ballot(s);
                if (lane == 0) kill[t] = w;
            }
        }
        __syncthreads();                               // B3
        // -- exact greedy 64-slot replay (wave0, verbatim) --
        if (wv == 0) {
            uint64_t suppressed = 0, keptmask = 0;
            for (int j2 = 0; j2 < st; ++j2) {
                if (!((suppressed >> j2) & 1ull)) {
                    keptmask |= 1ull << j2;
                    suppressed |= kill[j2];
                }
            }
            int k0 = kept_s;
            if ((keptmask >> lane) & 1ull) {
                int pos = k0 + __popcll(keptmask & ((1ull << lane) - 1ull));
                if (pos < MAXD) kpos[pos] = cand_s[lane];
            }
            int k1 = k0 + __popcll(keptmask);
            if (lane == 0) {
                fk0_s = k0;
                kept_s = k1;
                // cc<64 => refill stopped because raw exhausted => all consumed
                done_s = (k1 >= MAXD || cc < 64) ? 1 : 0;
            }
        }
        __syncthreads();                               // B4
        if (done_s) break;

        // -- refilter C[st, cc) vs NEW keeps [f0, f1), compact to front --
        {
            int f0 = fk0_s, f1 = kept_s;               // f1 - f0 <= st <= 64
            int j = st + tid;                          // cc - st <= 1023: 1/thread
            bool v = j < cc;
            int idx = v ? clist[j] : 0;
            float y1 = hy1[idx], x1 = hx1[idx], y2 = hy2[idx], x2 = hx2[idx], ar = har[idx];
            bool sup = false;
            for (int q0 = f0; q0 < f1; q0 += 64) {
                int qi = q0 + lane;
                int kp = (qi < f1) ? kpos[qi] : 0;
                float ky1 = hy1[kp], kx1 = hx1[kp], ky2 = hy2[kp], kx2 = hx2[kp], kar = har[kp];
                int qn = f1 - q0; if (qn > 64) qn = 64;
                bool deadall = false;
                for (int q = 0; q < qn; ++q) {
                    float qy1 = __shfl(ky1, q), qx1 = __shfl(kx1, q);
                    float qy2 = __shfl(ky2, q), qx2 = __shfl(kx2, q);
                    float qar = __shfl(kar, q);
                    float ih = fmaxf(0.f, fminf(y2, qy2) - fmaxf(y1, qy1));
                    float iw = fmaxf(0.f, fminf(x2, qx2) - fmaxf(x1, qx1));
                    float inter = ih * iw;
                    float uni = (ar + qar) - inter;
                    sup = sup || (inter > 0.f && (double)inter > (double)uni * IOUC);
                    if ((q & 7) == 7 && __ballot(v && !sup) == 0ull) { deadall = true; break; }
                }
                if (deadall) break;
            }
            bool srv = v && !sup;
            int sflag = srv ? 1 : 0;
            int inc = sflag;
            for (int off = 1; off < 64; off <<= 1) {
                int v2 = __shfl_up(inc, off);
                if (lane >= off) inc += v2;
            }
            if (lane == 63) wsumC[wv] = inc;
            __syncthreads();                           // B5: all clist reads done
            int base = 0, tot = 0;
            for (int w2 = 0; w2 < 16; ++w2) {
                int s2 = wsumC[w2];
                if (w2 < wv) base += s2;
                tot += s2;
            }
            if (srv) clist[base + (inc - sflag)] = idx;  // stable left-compact
            if (tid == 0) ccnt_s = tot;
            // next round's B1 publishes
        }
    }

    int kt = kept_s; if (kt > MAXD) kt = MAXD;
    if (tid == 0) cnt_out[b] = kt;
    if (tid < MAXD) kidx_out[b * MAXD + tid] = (tid < kt) ? og[kpos[tid]] : 0;
}

// ---------------------------------------------------------------------------
// K4: wide parallel gather (unchanged).
// ---------------------------------------------------------------------------
__global__ __launch_bounds__(256) void k_gather(const float* __restrict__ boxes,
                                                const float* __restrict__ probs,
                                                const int* __restrict__ kidx,
                                                const int* __restrict__ cnt,
                                                float* __restrict__ out_box,
                                                float* __restrict__ out_cls) {
    int u = blockIdx.x * 256 + threadIdx.x;
    if (u >= BB * PER_B) return;
    int b = u / PER_B;
    int r = u - b * PER_B;
    int count = cnt[b];
    float val = 0.0f;
    if (r < MAXD * 4) {
        int t = r >> 2, e = r & 3;
        if (t < count) {
            int idx = kidx[b * MAXD + t];
            val = boxes[((size_t)b * NN + idx) * 4 + e];
        }
        out_box[(size_t)b * MAXD * 4 + r] = val;
    } else {
        int q = r - MAXD * 4;
        int t = q / CC, c = q - t * CC;
        if (t < count) {
            int idx = kidx[b * MAXD + t];
            val = probs[((size_t)b * NN + idx) * CC + c];
        }
        out_cls[(size_t)b * MAXD * CC + q] = val;
    }
}

// ---------------------------------------------------------------------------
// FALLBACK (ws too small): round-4 fused k_nms — verified passing.
// ---------------------------------------------------------------------------
__global__ __launch_bounds__(1024) void k_nms_fb(uint64_t* keys,
                                                 const float* __restrict__ boxes,
                                                 int* __restrict__ kidx_out,
                                                 int* __restrict__ cnt_out) {
#pragma clang fp contract(off)
    __shared__ float sy1[SEGSZ], sx1[SEGSZ], sy2[SEGSZ], sx2[SEGSZ];
    __shared__ int   soidx[SEGSZ];
    __shared__ uint64_t bbuf[FBCAP];
    __shared__ uint64_t sup[NWORDS];
    __shared__ float ky1[MAXD], kx1[MAXD], ky2[MAXD], kx2[MAXD], kar[MAXD];
    __shared__ int   keptidx[MAXD];
    __shared__ int   wsumA[16], wsumB[16];
    __shared__ int   keptcnt_s, ctrl_s, seg_s;

    const int tid = threadIdx.x, lane = tid & 63, wv = tid >> 6;
    const int b = blockIdx.x;
    const uint64_t* kb = keys + (size_t)b * NN;
    const float* bxp = boxes + (size_t)b * NN * 4;
    int* og = (int*)(keys + (size_t)b * NN);

    uint64_t myk[4]; bool fa[4], fb[4];
    int asum = 0, bsum = 0;
    for (int k = 0; k < 4; ++k) {
        uint64_t key = kb[4 * tid + k]; myk[k] = key;
        unsigned hi = (unsigned)(key >> 32);
        fa[k] = (hi == 0x3F800000u);
        fb[k] = (__uint_as_float(hi) > CONF_T) && !fa[k];
        asum += fa[k] ? 1 : 0; bsum += fb[k] ? 1 : 0;
    }
    int ia = asum, ib = bsum;
    for (int off = 1; off < 64; off <<= 1) {
        int va = __shfl_up(ia, off), vb = __shfl_up(ib, off);
        if (lane >= off) { ia += va; ib += vb; }
    }
    if (lane == 63) { wsumA[wv] = ia; wsumB[wv] = ib; }
    __syncthreads();
    int baseA = 0, baseB = 0, cntA = 0, cntB = 0;
    for (int w2 = 0; w2 < 16; ++w2) {
        if (w2 < wv) { baseA += wsumA[w2]; baseB += wsumB[w2]; }
        cntA += wsumA[w2]; cntB += wsumB[w2];
    }
    int pA = baseA + (ia - asum);
    int pB = baseB + (ib - bsum);
    for (int k = 0; k < 4; ++k) {
        if (fa[k]) og[pA++] = 4 * tid + k;
        if (fb[k]) { if (pB < FBCAP) bbuf[pB] = myk[k]; pB++; }
    }
    int cntBc = cntB < FBCAP ? cntB : FBCAP;
    int nlist = cntA + cntBc;
    if (tid == 0) { keptcnt_s = 0; seg_s = 0; }
    for (int i = tid; i < FBCAP; i += 1024) if (i >= cntB) bbuf[i] = 0;
    __syncthreads();

    for (unsigned k2 = 2; k2 <= FBCAP; k2 <<= 1) {
        for (unsigned j = k2 >> 1; j > 0; j >>= 1) {
            for (unsigned i = tid; i < FBCAP; i += 1024) {
                unsigned p = i ^ j;
                if (p > i) {
                    uint64_t va = bbuf[i], vb = bbuf[p];
                    bool desc = ((i & k2) == 0);
                    if (desc ? (va < vb) : (va > vb)) { bbuf[i] = vb; bbuf[p] = va; }
                }
            }
            __syncthreads();
        }
    }
    for (int i = tid; i < cntBc; i += 1024)
        og[cntA + i] = (int)(0xFFFFFFFFu - (unsigned)(bbuf[i] & 0xFFFFFFFFull));
    if (tid < NWORDS) {
        int lo = tid * 64;
        uint64_t mm;
        if (nlist <= lo) mm = ~0ull;
        else if (nlist >= lo + 64) mm = 0ull;
        else mm = (~0ull) << (nlist - lo);
        sup[tid] = mm;
    }
    __syncthreads();

    for (int i = tid; i < SEGSZ; i += 1024) {
        if (i < nlist) {
            int o = og[i];
            soidx[i] = o;
            const float* bp = bxp + (size_t)o * 4;
            float b0 = bp[0], b1 = bp[1], b2 = bp[2], b3 = bp[3];
            sy1[i] = fminf(b0, b2); sy2[i] = fmaxf(b0, b2);
            sx1[i] = fminf(b1, b3); sx2[i] = fmaxf(b1, b3);
        }
    }
    __syncthreads();

    int curw = 0, segr = 0;
    while (true) {
        if (tid == 0) {
            int code = -1;
            for (;;) {
                int wend = (segr + 1) * (SEGSZ / 64);
                if (curw >= wend) {
                    if (segr == 0 && nlist > SEGSZ) {
                        code = -2; segr = 1; seg_s = 1; curw = SEGSZ / 64;
                    } else code = -1;
                    break;
                }
                uint64_t live = ~sup[curw];
                if (live) {
                    int j = __ffsll((unsigned long long)live) - 1;
                    int sel = curw * 64 + j;
                    int li = sel - segr * SEGSZ;
                    int kc = keptcnt_s;
                    keptidx[kc] = soidx[li];
                    ky1[kc] = sy1[li]; kx1[kc] = sx1[li];
                    ky2[kc] = sy2[li]; kx2[kc] = sx2[li];
                    kar[kc] = (sy2[li] - sy1[li]) * (sx2[li] - sx1[li]);
                    keptcnt_s = kc + 1;
                    sup[curw] |= (1ull << j);
                    code = (kc + 1 >= MAXD) ? -1 : sel;
                    break;
                }
                ++curw;
            }
            ctrl_s = code;
        }
        __syncthreads();
        int c = ctrl_s;
        if (c == -1) break;

        if (c == -2) {
            for (int i = tid; i < SEGSZ; i += 1024) {
                int gi = SEGSZ + i;
                if (gi < nlist) {
                    int o = og[gi];
                    soidx[i] = o;
                    const float* bp = bxp + (size_t)o * 4;
                    float b0 = bp[0], b1 = bp[1], b2 = bp[2], b3 = bp[3];
                    sy1[i] = fminf(b0, b2); sy2[i] = fmaxf(b0, b2);
                    sx1[i] = fminf(b1, b3); sx2[i] = fmaxf(b1, b3);
                }
            }
            __syncthreads();
            int kc = keptcnt_s;
            for (int k = 0; k < 2; ++k) {
                int li = tid + k * 1024;
                float y1 = sy1[li], y2 = sy2[li], x1 = sx1[li], x2 = sx2[li];
                float ar = (y2 - y1) * (x2 - x1);
                bool s = false;
                for (int q = 0; q < kc; ++q) {
                    float ih = fmaxf(0.f, fminf(y2, ky2[q]) - fmaxf(y1, ky1[q]));
                    float iw = fmaxf(0.f, fminf(x2, kx2[q]) - fmaxf(x1, kx1[q]));
                    float inter = ih * iw;
                    float uni = (ar + kar[q]) - inter;
                    s = s || (inter > 0.f && inter / uni > 0.5f);
                }
                uint64_t bal = __ballot(s);
                if (lane == 0 && bal) {
                    int word = (SEGSZ + k * 1024 + wv * 64) >> 6;
                    sup[word] |= bal;
                }
            }
            __syncthreads();
            continue;
        }

        int sg = seg_s;
        int cl = c - sg * SEGSZ;
        float cy1 = sy1[cl], cy2 = sy2[cl], cx1 = sx1[cl], cx2 = sx2[cl];
        float car = (cy2 - cy1) * (cx2 - cx1);
        for (int k = 0; k < 2; ++k) {
            int li = tid + k * 1024;
            float y1 = sy1[li], y2 = sy2[li], x1 = sx1[li], x2 = sx2[li];
            float ar = (y2 - y1) * (x2 - x1);
            float ih = fmaxf(0.f, fminf(y2, cy2) - fmaxf(y1, cy1));
            float iw = fmaxf(0.f, fminf(x2, cx2) - fmaxf(x1, cx1));
            float inter = ih * iw;
            float uni = (ar + car) - inter;
            bool s = (inter > 0.f) && (inter / uni > 0.5f);
            uint64_t bal = __ballot(s);
            if (lane == 0 && bal) {
                int word = (sg * SEGSZ + k * 1024 + wv * 64) >> 6;
                sup[word] |= bal;
            }
        }
        __syncthreads();
    }

    if (tid == 0) cnt_out[b] = keptcnt_s;
    for (int i = tid; i < MAXD; i += 1024)
        kidx_out[b * MAXD + i] = (i < keptcnt_s) ? keptidx[i] : 0;
}

extern "C" void kernel_launch(void* const* d_in, const int* in_sizes, int n_in,
                              void* d_out, int out_size, void* d_ws, size_t ws_size,
                              hipStream_t stream) {
    const float* boxes = (const float*)d_in[0];   // [B,N,4]
    const float* cls   = (const float*)d_in[1];   // [B,N,C]
    float* out = (float*)d_out;
    float* out_box = out;                                                  // [B,100,4]
    float* out_cls = out + (size_t)BB * MAXD * 4;                          // [B,100,80]
    float* probs   = out + (size_t)BB * MAXD * 4 + (size_t)BB * MAXD * CC; // [B,N,80]

    char* ws = (char*)d_ws;
    uint64_t* keys = (uint64_t*)(ws + WS_KEYS);

    k_softmax<<<(BB * NN) / 128, 128, 0, stream>>>(cls, probs, keys);

    if (ws_size >= (size_t)WS_NEED) {
        int* kidx  = (int*)(ws + WS_KIDX);
        int* cnt   = (int*)(ws + WS_CNT);

        k_pnms<<<BB, 1024, 0, stream>>>(keys, boxes, kidx, cnt);
        k_gather<<<(BB * PER_B + 255) / 256, 256, 0, stream>>>(boxes, probs, kidx, cnt,
                                                               out_box, out_cls);
    } else {
        int* kidx = (int*)(ws + (size_t)BB * NN * sizeof(uint64_t));
        int* cnt  = kidx + BB * MAXD;
        k_nms_fb<<<BB, 1024, 0, stream>>>(keys, boxes, kidx, cnt);
        k_gather<<<(BB * PER_B + 255) / 256, 256, 0, stream>>>(boxes, probs, kidx, cnt,
                                                               out_box, out_cls);
    }
}

// Round 2
// 116.382 us; speedup vs baseline: 1.5202x; 1.0654x over previous
//
#include <hip/hip_runtime.h>
#include <cstdint>
#include <cstddef>

#define BB 16
#define NN 4096
#define CC 80
#define MAXD 100
#define CONF_T 0.5f
#define PER_B (MAXD * 4 + MAXD * CC)   // 8400 output elems per batch
#define NWORDS 64                      // 4096/64 bitmap words (fallback)
#define FBCAP 2048                     // fallback kernel's capacity
#define SEGSZ 2048
#define CH 1024                        // lazy-refill chunk (1 entry/thread)
#define CCAP 1088                      // clean-list cap: 63 leftover + 1024 chunk

// fl32(inter/uni) > 0.5  <=>  inter > uni*(0.5+2^-25), evaluated EXACTLY in
// fp64 (24-bit x 25-bit mantissa product = 49 bits < 53). Bit-identical to
// the reference's IEEE divide + compare. (verified passing rounds 9)
#define IOUC 0x1.000001p-1

// ---- workspace layout ----
#define WS_KEYS   0x000000             // [B*N] u64
#define WS_NEED   0x200000             // 2 MB

// ---------------------------------------------------------------------------
// K1: softmax of (10x)^2 per row — 8 LANES per row, all-register, no LDS.
// Lane j owns elements {j, j+8, ..., j+72}: exactly the numpy pairwise-8
// groups, so the sequential per-lane accumulation == r8[j] chain bitwise.
// Cross-lane max: fmaxf is commutative/associative over finite z>=0 (any
// order -> same bits). Cross-lane sum: shfl_xor tree reproduces
// ((r0+r1)+(r2+r3))+((r4+r5)+(r6+r7)) with identical operand pairing
// (IEEE add commutative -> lane-swapped order same bits).
// ---------------------------------------------------------------------------
__global__ __launch_bounds__(256) void k_softmax(const float* __restrict__ cls_in,
                                                 float* __restrict__ probs,
                                                 uint64_t* __restrict__ keys) {
#pragma clang fp contract(off)
    int slot = blockIdx.x * 256 + threadIdx.x;   // 8 slots per row
    int row  = slot >> 3;                        // [0, B*N)
    int j    = slot & 7;
    const float* rp = cls_in + (size_t)row * CC + j;

    float e[10];
    float m = -3.402823466e+38f;
    #pragma unroll
    for (int k = 0; k < 10; ++k) {
        float y = rp[8 * k] * 10.0f;
        float z = y * y;
        e[k] = z;
        m = fmaxf(m, z);
    }
    m = fmaxf(m, __shfl_xor(m, 1));
    m = fmaxf(m, __shfl_xor(m, 2));
    m = fmaxf(m, __shfl_xor(m, 4));

    #pragma unroll
    for (int k = 0; k < 10; ++k) e[k] = expf(e[k] - m);

    float acc = e[0];
    #pragma unroll
    for (int k = 1; k < 10; ++k) acc += e[k];    // r8[j] sequential chain
    acc = acc + __shfl_xor(acc, 1);              // (r0+r1) ...
    acc = acc + __shfl_xor(acc, 2);              // (r0+r1)+(r2+r3) ...
    acc = acc + __shfl_xor(acc, 4);              // full pairwise tree

    float score = 1.0f / acc;
    float* pp = probs + (size_t)row * CC + j;
    #pragma unroll
    for (int k = 0; k < 10; ++k) pp[8 * k] = e[k] * score;

    if (j == 0) {
        unsigned n = (unsigned)(row & (NN - 1));
        keys[row] = ((uint64_t)__float_as_uint(score) << 32)
                  | (uint64_t)(0xFFFFFFFFu - n);
    }
}

// ---------------------------------------------------------------------------
// K2 (fused): partition + rank-sort + LDS corner build + LAZY-LIST NMS
//             + fused output gather (replaces separate k_gather dispatch).
// One block (1024 thr = 16 waves) per batch.
//
// Clean list C holds, in ascending sorted order, all live candidates with
// position < cursor, each already checked vs every keep so far. Raw
// candidates are implicit: positions [cursor, nl). Per round:
//   refill: while |C|<64 and raw left, filter next 1024 raw vs ALL keeps,
//           stable-append survivors to C (first chunk: 0 keeps = free)
//   select: C[0..st) = st lowest live overall (raw entries are all >= cursor)
//   kill matrix + exact greedy replay: verbatim from the verified kernel
//   refilter: C[st..cc) vs only the NEW keeps, stable-compact to front
// done <=> kept>=100 or cc<64 (refill exhausted raw). Identical greedy order
// to the reference: keeps appended in ascending sorted position.
// ---------------------------------------------------------------------------
__global__ __launch_bounds__(1024) void k_pnms(const uint64_t* __restrict__ keys,
                                               const float* __restrict__ boxes,
                                               const float* __restrict__ probs,
                                               float* __restrict__ out_box,
                                               float* __restrict__ out_cls) {
#pragma clang fp contract(off)
    __shared__ __align__(16) unsigned char sraw[6 * NN * 4];   // 96 KB
    float* hy1 = (float*)sraw;
    float* hx1 = (float*)(sraw + NN * 4);
    float* hy2 = (float*)(sraw + 2 * NN * 4);
    float* hx2 = (float*)(sraw + 3 * NN * 4);
    float* har = (float*)(sraw + 4 * NN * 4);
    int*   og  = (int*)(sraw + 5 * NN * 4);
    uint64_t* bbuf = (uint64_t*)sraw;          // overlays hy1+hx1 (32 KB); dead after sort
    __shared__ int clist[CCAP];
    __shared__ uint64_t kill[64];
    __shared__ int cand_s[64];
    __shared__ int kpos[MAXD];
    __shared__ int wsumA[16], wsumB[16], wsumC[16];
    __shared__ int kept_s, fk0_s, done_s, ccnt_s, cur_s;

    const int tid = threadIdx.x, lane = tid & 63, wv = tid >> 6;
    const int b = blockIdx.x;
    const uint64_t* kb = keys + (size_t)b * NN;
    const float* bxp = boxes + (size_t)b * NN * 4;

    // ---- partition (og/bbuf in LDS, keys untouched) ----
    uint64_t myk[4]; bool fa[4], fb[4];
    int asum = 0, bsum = 0;
    for (int k = 0; k < 4; ++k) {
        uint64_t key = kb[4 * tid + k]; myk[k] = key;
        unsigned hi = (unsigned)(key >> 32);
        fa[k] = (hi == 0x3F800000u);
        fb[k] = (__uint_as_float(hi) > CONF_T) && !fa[k];
        asum += fa[k] ? 1 : 0; bsum += fb[k] ? 1 : 0;
    }
    int ia = asum, ib = bsum;                       // wave-inclusive scans
    for (int off = 1; off < 64; off <<= 1) {
        int va = __shfl_up(ia, off), vb = __shfl_up(ib, off);
        if (lane >= off) { ia += va; ib += vb; }
    }
    if (lane == 63) { wsumA[wv] = ia; wsumB[wv] = ib; }
    __syncthreads();
    int baseA = 0, baseB = 0, cntA = 0, cntB = 0;
    for (int w2 = 0; w2 < 16; ++w2) {
        if (w2 < wv) { baseA += wsumA[w2]; baseB += wsumB[w2]; }
        cntA += wsumA[w2]; cntB += wsumB[w2];
    }
    int pA = baseA + (ia - asum);
    int pB = baseB + (ib - bsum);
    for (int k = 0; k < 4; ++k) {
        if (fa[k]) og[pA++] = 4 * tid + k;          // stable: idx order
        if (fb[k]) bbuf[pB++] = myk[k];             // pB < cntB <= 4096 always
    }
    __syncthreads();

    // ---- rank sort of B (descending, keys unique): one barrier ----
    for (int i = tid; i < cntB; i += 1024) {
        uint64_t ki = bbuf[i];
        int rank = 0;
        for (int j = 0; j < cntB; ++j) rank += (bbuf[j] > ki) ? 1 : 0;
        og[cntA + rank] = (int)(0xFFFFFFFFu - (unsigned)(ki & 0xFFFFFFFFull));
    }
    int nl = cntA + cntB; if (nl > NN) nl = NN;
    __syncthreads();   // bbuf reads done; og complete

    // ---- sorted corner build into LDS (overwrites bbuf region) ----
    for (int i = tid; i < nl; i += 1024) {
        int o = og[i];
        float4 bv = ((const float4*)bxp)[o];
        float y1 = fminf(bv.x, bv.z), y2 = fmaxf(bv.x, bv.z);
        float x1 = fminf(bv.y, bv.w), x2 = fmaxf(bv.y, bv.w);
        hy1[i] = y1; hx1[i] = x1; hy2[i] = y2; hx2[i] = x2;
        har[i] = (y2 - y1) * (x2 - x1);
    }
    if (tid == 0) { kept_s = 0; fk0_s = 0; done_s = 0; ccnt_s = 0; cur_s = 0; }

    // ---- rounds ----
    for (;;) {
        __syncthreads();                               // B1
        // -- refill clean list from raw [cursor, nl) --
        for (;;) {
            int cc0 = ccnt_s, cur = cur_s;
            if (cc0 >= 64 || cur >= nl) break;         // uniform
            int i = cur + tid;
            bool v = i < nl;
            int ii = v ? i : 0;
            float y1 = hy1[ii], x1 = hx1[ii], y2 = hy2[ii], x2 = hx2[ii], ar = har[ii];
            bool sup = false;
            int f1 = kept_s;                           // < MAXD here (else done)
            for (int q0 = 0; q0 < f1; q0 += 64) {
                int qi = q0 + lane;
                int kp = (qi < f1) ? kpos[qi] : 0;
                float ky1 = hy1[kp], kx1 = hx1[kp], ky2 = hy2[kp], kx2 = hx2[kp], kar = har[kp];
                int qn = f1 - q0; if (qn > 64) qn = 64;
                bool deadall = false;
                for (int q = 0; q < qn; ++q) {
                    float qy1 = __shfl(ky1, q), qx1 = __shfl(kx1, q);
                    float qy2 = __shfl(ky2, q), qx2 = __shfl(kx2, q);
                    float qar = __shfl(kar, q);
                    float ih = fmaxf(0.f, fminf(y2, qy2) - fmaxf(y1, qy1));
                    float iw = fmaxf(0.f, fminf(x2, qx2) - fmaxf(x1, qx1));
                    float inter = ih * iw;
                    float uni = (ar + qar) - inter;
                    sup = sup || (inter > 0.f && (double)inter > (double)uni * IOUC);
                    if ((q & 7) == 7 && __ballot(v && !sup) == 0ull) { deadall = true; break; }
                }
                if (deadall) break;
            }
            bool srv = v && !sup;
            int sflag = srv ? 1 : 0;
            int inc = sflag;
            for (int off = 1; off < 64; off <<= 1) {
                int v2 = __shfl_up(inc, off);
                if (lane >= off) inc += v2;
            }
            if (lane == 63) wsumC[wv] = inc;
            __syncthreads();                           // BA: scan ready, reads done
            int base = 0, tot = 0;
            for (int w2 = 0; w2 < 16; ++w2) {
                int s2 = wsumC[w2];
                if (w2 < wv) base += s2;
                tot += s2;
            }
            if (srv) clist[cc0 + base + (inc - sflag)] = i;   // stable append
            if (tid == 0) { ccnt_s = cc0 + tot; cur_s = cur + CH; }
            __syncthreads();                           // BB: writes visible
        }
        int cc = ccnt_s;
        int st = cc < 64 ? cc : 64;
        if (tid < 64) cand_s[tid] = (tid < st) ? clist[tid] : -1;
        __syncthreads();                               // B2
        if (st <= 0) break;

        // -- 64x64 intra-batch kill matrix: wave w rows t = w+16r (verbatim) --
        {
            int cj = cand_s[lane];
            bool jv = cj >= 0;
            int cjx = jv ? cj : 0;
            float jy1 = hy1[cjx], jx1 = hx1[cjx], jy2 = hy2[cjx], jx2 = hx2[cjx], jar = har[cjx];
            #pragma unroll
            for (int r = 0; r < 4; ++r) {
                int t = wv + 16 * r;
                int ct = cand_s[t];
                bool tv = ct >= 0;
                int ctx = tv ? ct : 0;
                float ty1 = hy1[ctx], tx1 = hx1[ctx], ty2 = hy2[ctx], tx2 = hx2[ctx], tar = har[ctx];
                float ih = fmaxf(0.f, fminf(ty2, jy2) - fmaxf(ty1, jy1));
                float iw = fmaxf(0.f, fminf(tx2, jx2) - fmaxf(tx1, jx1));
                float inter = ih * iw;
                float uni = (tar + jar) - inter;
                bool s = tv && jv && (inter > 0.f) && ((double)inter > (double)uni * IOUC);
                uint64_t w = __ballot(s);
                if (lane == 0) kill[t] = w;
            }
        }
        __syncthreads();                               // B3
        // -- exact greedy 64-slot replay (wave0, verbatim) --
        if (wv == 0) {
            uint64_t suppressed = 0, keptmask = 0;
            for (int j2 = 0; j2 < st; ++j2) {
                if (!((suppressed >> j2) & 1ull)) {
                    keptmask |= 1ull << j2;
                    suppressed |= kill[j2];
                }
            }
            int k0 = kept_s;
            if ((keptmask >> lane) & 1ull) {
                int pos = k0 + __popcll(keptmask & ((1ull << lane) - 1ull));
                if (pos < MAXD) kpos[pos] = cand_s[lane];
            }
            int k1 = k0 + __popcll(keptmask);
            if (lane == 0) {
                fk0_s = k0;
                kept_s = k1;
                // cc<64 => refill stopped because raw exhausted => all consumed
                done_s = (k1 >= MAXD || cc < 64) ? 1 : 0;
            }
        }
        __syncthreads();                               // B4
        if (done_s) break;

        // -- refilter C[st, cc) vs NEW keeps [f0, f1), compact to front --
        {
            int f0 = fk0_s, f1 = kept_s;               // f1 - f0 <= st <= 64
            int j = st + tid;                          // cc - st <= 1023: 1/thread
            bool v = j < cc;
            int idx = v ? clist[j] : 0;
            float y1 = hy1[idx], x1 = hx1[idx], y2 = hy2[idx], x2 = hx2[idx], ar = har[idx];
            bool sup = false;
            for (int q0 = f0; q0 < f1; q0 += 64) {
                int qi = q0 + lane;
                int kp = (qi < f1) ? kpos[qi] : 0;
                float ky1 = hy1[kp], kx1 = hx1[kp], ky2 = hy2[kp], kx2 = hx2[kp], kar = har[kp];
                int qn = f1 - q0; if (qn > 64) qn = 64;
                bool deadall = false;
                for (int q = 0; q < qn; ++q) {
                    float qy1 = __shfl(ky1, q), qx1 = __shfl(kx1, q);
                    float qy2 = __shfl(ky2, q), qx2 = __shfl(kx2, q);
                    float qar = __shfl(kar, q);
                    float ih = fmaxf(0.f, fminf(y2, qy2) - fmaxf(y1, qy1));
                    float iw = fmaxf(0.f, fminf(x2, qx2) - fmaxf(x1, qx1));
                    float inter = ih * iw;
                    float uni = (ar + qar) - inter;
                    sup = sup || (inter > 0.f && (double)inter > (double)uni * IOUC);
                    if ((q & 7) == 7 && __ballot(v && !sup) == 0ull) { deadall = true; break; }
                }
                if (deadall) break;
            }
            bool srv = v && !sup;
            int sflag = srv ? 1 : 0;
            int inc = sflag;
            for (int off = 1; off < 64; off <<= 1) {
                int v2 = __shfl_up(inc, off);
                if (lane >= off) inc += v2;
            }
            if (lane == 63) wsumC[wv] = inc;
            __syncthreads();                           // B5: all clist reads done
            int base = 0, tot = 0;
            for (int w2 = 0; w2 < 16; ++w2) {
                int s2 = wsumC[w2];
                if (w2 < wv) base += s2;
                tot += s2;
            }
            if (srv) clist[base + (inc - sflag)] = idx;  // stable left-compact
            if (tid == 0) ccnt_s = tot;
            // next round's B1 publishes
        }
    }

    // ---- fused output gather (exact k_gather semantics) ----
    int kt = kept_s; if (kt > MAXD) kt = MAXD;
    if (tid < MAXD) clist[tid] = (tid < kt) ? og[kpos[tid]] : 0;
    __syncthreads();

    float* ob = out_box + (size_t)b * MAXD * 4;
    float* oc = out_cls + (size_t)b * MAXD * CC;
    const float* pb = probs + (size_t)b * NN * CC;
    for (int r = tid; r < MAXD * 4; r += 1024) {
        int t = r >> 2, e2 = r & 3;
        float val = 0.0f;
        if (t < kt) { int idx = clist[t]; val = bxp[(size_t)idx * 4 + e2]; }
        ob[r] = val;
    }
    for (int q = tid; q < MAXD * CC; q += 1024) {
        int t = q / CC, c = q - t * CC;
        float val = 0.0f;
        if (t < kt) { int idx = clist[t]; val = pb[(size_t)idx * CC + c]; }
        oc[q] = val;
    }
}

// ---------------------------------------------------------------------------
// K4: wide parallel gather (fallback path only).
// ---------------------------------------------------------------------------
__global__ __launch_bounds__(256) void k_gather(const float* __restrict__ boxes,
                                                const float* __restrict__ probs,
                                                const int* __restrict__ kidx,
                                                const int* __restrict__ cnt,
                                                float* __restrict__ out_box,
                                                float* __restrict__ out_cls) {
    int u = blockIdx.x * 256 + threadIdx.x;
    if (u >= BB * PER_B) return;
    int b = u / PER_B;
    int r = u - b * PER_B;
    int count = cnt[b];
    float val = 0.0f;
    if (r < MAXD * 4) {
        int t = r >> 2, e = r & 3;
        if (t < count) {
            int idx = kidx[b * MAXD + t];
            val = boxes[((size_t)b * NN + idx) * 4 + e];
        }
        out_box[(size_t)b * MAXD * 4 + r] = val;
    } else {
        int q = r - MAXD * 4;
        int t = q / CC, c = q - t * CC;
        if (t < count) {
            int idx = kidx[b * MAXD + t];
            val = probs[((size_t)b * NN + idx) * CC + c];
        }
        out_cls[(size_t)b * MAXD * CC + q] = val;
    }
}

// ---------------------------------------------------------------------------
// FALLBACK (ws too small): round-4 fused k_nms — verified passing.
// ---------------------------------------------------------------------------
__global__ __launch_bounds__(1024) void k_nms_fb(uint64_t* keys,
                                                 const float* __restrict__ boxes,
                                                 int* __restrict__ kidx_out,
                                                 int* __restrict__ cnt_out) {
#pragma clang fp contract(off)
    __shared__ float sy1[SEGSZ], sx1[SEGSZ], sy2[SEGSZ], sx2[SEGSZ];
    __shared__ int   soidx[SEGSZ];
    __shared__ uint64_t bbuf[FBCAP];
    __shared__ uint64_t sup[NWORDS];
    __shared__ float ky1[MAXD], kx1[MAXD], ky2[MAXD], kx2[MAXD], kar[MAXD];
    __shared__ int   keptidx[MAXD];
    __shared__ int   wsumA[16], wsumB[16];
    __shared__ int   keptcnt_s, ctrl_s, seg_s;

    const int tid = threadIdx.x, lane = tid & 63, wv = tid >> 6;
    const int b = blockIdx.x;
    const uint64_t* kb = keys + (size_t)b * NN;
    const float* bxp = boxes + (size_t)b * NN * 4;
    int* og = (int*)(keys + (size_t)b * NN);

    uint64_t myk[4]; bool fa[4], fb[4];
    int asum = 0, bsum = 0;
    for (int k = 0; k < 4; ++k) {
        uint64_t key = kb[4 * tid + k]; myk[k] = key;
        unsigned hi = (unsigned)(key >> 32);
        fa[k] = (hi == 0x3F800000u);
        fb[k] = (__uint_as_float(hi) > CONF_T) && !fa[k];
        asum += fa[k] ? 1 : 0; bsum += fb[k] ? 1 : 0;
    }
    int ia = asum, ib = bsum;
    for (int off = 1; off < 64; off <<= 1) {
        int va = __shfl_up(ia, off), vb = __shfl_up(ib, off);
        if (lane >= off) { ia += va; ib += vb; }
    }
    if (lane == 63) { wsumA[wv] = ia; wsumB[wv] = ib; }
    __syncthreads();
    int baseA = 0, baseB = 0, cntA = 0, cntB = 0;
    for (int w2 = 0; w2 < 16; ++w2) {
        if (w2 < wv) { baseA += wsumA[w2]; baseB += wsumB[w2]; }
        cntA += wsumA[w2]; cntB += wsumB[w2];
    }
    int pA = baseA + (ia - asum);
    int pB = baseB + (ib - bsum);
    for (int k = 0; k < 4; ++k) {
        if (fa[k]) og[pA++] = 4 * tid + k;
        if (fb[k]) { if (pB < FBCAP) bbuf[pB] = myk[k]; pB++; }
    }
    int cntBc = cntB < FBCAP ? cntB : FBCAP;
    int nlist = cntA + cntBc;
    if (tid == 0) { keptcnt_s = 0; seg_s = 0; }
    for (int i = tid; i < FBCAP; i += 1024) if (i >= cntB) bbuf[i] = 0;
    __syncthreads();

    for (unsigned k2 = 2; k2 <= FBCAP; k2 <<= 1) {
        for (unsigned j = k2 >> 1; j > 0; j >>= 1) {
            for (unsigned i = tid; i < FBCAP; i += 1024) {
                unsigned p = i ^ j;
                if (p > i) {
                    uint64_t va = bbuf[i], vb = bbuf[p];
                    bool desc = ((i & k2) == 0);
                    if (desc ? (va < vb) : (va > vb)) { bbuf[i] = vb; bbuf[p] = va; }
                }
            }
            __syncthreads();
        }
    }
    for (int i = tid; i < cntBc; i += 1024)
        og[cntA + i] = (int)(0xFFFFFFFFu - (unsigned)(bbuf[i] & 0xFFFFFFFFull));
    if (tid < NWORDS) {
        int lo = tid * 64;
        uint64_t mm;
        if (nlist <= lo) mm = ~0ull;
        else if (nlist >= lo + 64) mm = 0ull;
        else mm = (~0ull) << (nlist - lo);
        sup[tid] = mm;
    }
    __syncthreads();

    for (int i = tid; i < SEGSZ; i += 1024) {
        if (i < nlist) {
            int o = og[i];
            soidx[i] = o;
            const float* bp = bxp + (size_t)o * 4;
            float b0 = bp[0], b1 = bp[1], b2 = bp[2], b3 = bp[3];
            sy1[i] = fminf(b0, b2); sy2[i] = fmaxf(b0, b2);
            sx1[i] = fminf(b1, b3); sx2[i] = fmaxf(b1, b3);
        }
    }
    __syncthreads();

    int curw = 0, segr = 0;
    while (true) {
        if (tid == 0) {
            int code = -1;
            for (;;) {
                int wend = (segr + 1) * (SEGSZ / 64);
                if (curw >= wend) {
                    if (segr == 0 && nlist > SEGSZ) {
                        code = -2; segr = 1; seg_s = 1; curw = SEGSZ / 64;
                    } else code = -1;
                    break;
                }
                uint64_t live = ~sup[curw];
                if (live) {
                    int j = __ffsll((unsigned long long)live) - 1;
                    int sel = curw * 64 + j;
                    int li = sel - segr * SEGSZ;
                    int kc = keptcnt_s;
                    keptidx[kc] = soidx[li];
                    ky1[kc] = sy1[li]; kx1[kc] = sx1[li];
                    ky2[kc] = sy2[li]; kx2[kc] = sx2[li];
                    kar[kc] = (sy2[li] - sy1[li]) * (sx2[li] - sx1[li]);
                    keptcnt_s = kc + 1;
                    sup[curw] |= (1ull << j);
                    code = (kc + 1 >= MAXD) ? -1 : sel;
                    break;
                }
                ++curw;
            }
            ctrl_s = code;
        }
        __syncthreads();
        int c = ctrl_s;
        if (c == -1) break;

        if (c == -2) {
            for (int i = tid; i < SEGSZ; i += 1024) {
                int gi = SEGSZ + i;
                if (gi < nlist) {
                    int o = og[gi];
                    soidx[i] = o;
                    const float* bp = bxp + (size_t)o * 4;
                    float b0 = bp[0], b1 = bp[1], b2 = bp[2], b3 = bp[3];
                    sy1[i] = fminf(b0, b2); sy2[i] = fmaxf(b0, b2);
                    sx1[i] = fminf(b1, b3); sx2[i] = fmaxf(b1, b3);
                }
            }
            __syncthreads();
            int kc = keptcnt_s;
            for (int k = 0; k < 2; ++k) {
                int li = tid + k * 1024;
                float y1 = sy1[li], y2 = sy2[li], x1 = sx1[li], x2 = sx2[li];
                float ar = (y2 - y1) * (x2 - x1);
                bool s = false;
                for (int q = 0; q < kc; ++q) {
                    float ih = fmaxf(0.f, fminf(y2, ky2[q]) - fmaxf(y1, ky1[q]));
                    float iw = fmaxf(0.f, fminf(x2, kx2[q]) - fmaxf(x1, kx1[q]));
                    float inter = ih * iw;
                    float uni = (ar + kar[q]) - inter;
                    s = s || (inter > 0.f && inter / uni > 0.5f);
                }
                uint64_t bal = __ballot(s);
                if (lane == 0 && bal) {
                    int word = (SEGSZ + k * 1024 + wv * 64) >> 6;
                    sup[word] |= bal;
                }
            }
            __syncthreads();
            continue;
        }

        int sg = seg_s;
        int cl = c - sg * SEGSZ;
        float cy1 = sy1[cl], cy2 = sy2[cl], cx1 = sx1[cl], cx2 = sx2[cl];
        float car = (cy2 - cy1) * (cx2 - cx1);
        for (int k = 0; k < 2; ++k) {
            int li = tid + k * 1024;
            float y1 = sy1[li], y2 = sy2[li], x1 = sx1[li], x2 = sx2[li];
            float ar = (y2 - y1) * (x2 - x1);
            float ih = fmaxf(0.f, fminf(y2, cy2) - fmaxf(y1, cy1));
            float iw = fmaxf(0.f, fminf(x2, cx2) - fmaxf(x1, cx1));
            float inter = ih * iw;
            float uni = (ar + car) - inter;
            bool s = (inter > 0.f) && (inter / uni > 0.5f);
            uint64_t bal = __ballot(s);
            if (lane == 0 && bal) {
                int word = (sg * SEGSZ + k * 1024 + wv * 64) >> 6;
                sup[word] |= bal;
            }
        }
        __syncthreads();
    }

    if (tid == 0) cnt_out[b] = keptcnt_s;
    for (int i = tid; i < MAXD; i += 1024)
        kidx_out[b * MAXD + i] = (i < keptcnt_s) ? keptidx[i] : 0;
}

extern "C" void kernel_launch(void* const* d_in, const int* in_sizes, int n_in,
                              void* d_out, int out_size, void* d_ws, size_t ws_size,
                              hipStream_t stream) {
    const float* boxes = (const float*)d_in[0];   // [B,N,4]
    const float* cls   = (const float*)d_in[1];   // [B,N,C]
    float* out = (float*)d_out;
    float* out_box = out;                                                  // [B,100,4]
    float* out_cls = out + (size_t)BB * MAXD * 4;                          // [B,100,80]
    float* probs   = out + (size_t)BB * MAXD * 4 + (size_t)BB * MAXD * CC; // [B,N,80]

    char* ws = (char*)d_ws;
    uint64_t* keys = (uint64_t*)(ws + WS_KEYS);

    k_softmax<<<(BB * NN * 8) / 256, 256, 0, stream>>>(cls, probs, keys);

    if (ws_size >= (size_t)WS_NEED) {
        k_pnms<<<BB, 1024, 0, stream>>>(keys, boxes, probs, out_box, out_cls);
    } else {
        int* kidx = (int*)(ws + (size_t)BB * NN * sizeof(uint64_t));
        int* cnt  = kidx + BB * MAXD;
        k_nms_fb<<<BB, 1024, 0, stream>>>(keys, boxes, kidx, cnt);
        k_gather<<<(BB * PER_B + 255) / 256, 256, 0, stream>>>(boxes, probs, kidx, cnt,
                                                               out_box, out_cls);
    }
}